// Round 7
// baseline (146.112 us; speedup 1.0000x reference)
//
#include <hip/hip_runtime.h>

typedef __attribute__((ext_vector_type(8))) short short8;
typedef __attribute__((ext_vector_type(4))) float f32x4;

#define BB 2
#define TT 2048
#define HH 16
#define DD 64
#define CC 1024

__device__ __forceinline__ unsigned short f2bf(float f) {
  union { float f; unsigned int u; } v; v.f = f;
  unsigned int r = v.u + 0x7fffu + ((v.u >> 16) & 1u);
  return (unsigned short)(r >> 16);
}
__device__ __forceinline__ float bf2f(unsigned short h) {
  union { unsigned int u; float f; } v; v.u = ((unsigned int)h) << 16; return v.f;
}
__device__ __forceinline__ unsigned int cvtpk(float lo, float hi) {
  unsigned int r;
  asm("v_cvt_pk_bf16_f32 %0, %1, %2" : "=v"(r) : "v"(lo), "v"(hi));
  return r;
}

__global__ void cvt_f32_bf16(const float* __restrict__ in, unsigned short* __restrict__ out, int n) {
  int i = blockIdx.x * blockDim.x + threadIdx.x;
  int stride = gridDim.x * blockDim.x;
  for (; i < n; i += stride) out[i] = f2bf(in[i]);
}

// C = A @ B^T ; 128^2 tile, global_load_lds staging, LDS DOUBLE-BUFFERED:
// stage(kt+1 -> db^1) issued BEFORE compute(kt from db); the single barrier's
// vmcnt(0) then drains loads that are a full compute-phase old (~free).
template<bool BF16OUT>
__global__ __launch_bounds__(256) void gemm_bt(const unsigned short* __restrict__ A,
                                               const unsigned short* __restrict__ B,
                                               void* __restrict__ Cv,
                                               int M, int N, int K) {
  __shared__ unsigned short As[2][128 * 64];
  __shared__ unsigned short Bs[2][128 * 64];
  const int bm = blockIdx.y * 128, bn = blockIdx.x * 128;
  const int tid = threadIdx.x, wave = tid >> 6, lane = tid & 63;
  const int wm = (wave >> 1) * 64, wn = (wave & 1) * 64;
  const int g = lane >> 4, lr = lane & 15;
  f32x4 acc[4][4];
  #pragma unroll
  for (int i = 0; i < 4; ++i)
    #pragma unroll
    for (int j = 0; j < 4; ++j) acc[i][j] = (f32x4){0.f, 0.f, 0.f, 0.f};

  const int srow = lane >> 3, scol = (lane & 7) * 8;

#define GSTAGE(DB, K0)                                                                    \
  {                                                                                       \
    _Pragma("unroll")                                                                     \
    for (int c = 0; c < 4; ++c) {                                                         \
      const int chunk = wave * 4 + c;                                                     \
      const int row = chunk * 8 + srow;                                                   \
      __builtin_amdgcn_global_load_lds(                                                   \
        (const __attribute__((address_space(1))) void*)&A[(size_t)(bm + row) * K + (K0) + scol], \
        (__attribute__((address_space(3))) void*)&As[DB][chunk * 512], 16, 0, 0);         \
      __builtin_amdgcn_global_load_lds(                                                   \
        (const __attribute__((address_space(1))) void*)&B[(size_t)(bn + row) * K + (K0) + scol], \
        (__attribute__((address_space(3))) void*)&Bs[DB][chunk * 512], 16, 0, 0);         \
    }                                                                                     \
  }

  GSTAGE(0, 0);
  __syncthreads();
  const int nkt = K >> 6;
  for (int kt = 0; kt < nkt; ++kt) {
    const int db = kt & 1;
    if (kt + 1 < nkt) GSTAGE(db ^ 1, (kt + 1) << 6);   // fire-and-forget into other buffer
    #pragma unroll
    for (int kk = 0; kk < 64; kk += 32) {
      const int kb = kk + g * 8;
      short8 af[4], bf[4];
      #pragma unroll
      for (int i = 0; i < 4; ++i) {
        af[i] = *(const short8*)&As[db][(wm + i * 16 + lr) * 64 + kb];
        bf[i] = *(const short8*)&Bs[db][(wn + i * 16 + lr) * 64 + kb];
      }
      __builtin_amdgcn_s_setprio(1);
      #pragma unroll
      for (int i = 0; i < 4; ++i)
        #pragma unroll
        for (int j = 0; j < 4; ++j)
          acc[i][j] = __builtin_amdgcn_mfma_f32_16x16x32_bf16(af[i], bf[j], acc[i][j], 0, 0, 0);
      __builtin_amdgcn_s_setprio(0);
    }
    __syncthreads();   // drains this wave's (old) staging loads + all reads of db
  }
#undef GSTAGE

  #pragma unroll
  for (int i = 0; i < 4; ++i) {
    const int row0 = bm + wm + i * 16 + g * 4;
    #pragma unroll
    for (int j = 0; j < 4; ++j) {
      const int col = bn + wn + j * 16 + lr;
      #pragma unroll
      for (int r = 0; r < 4; ++r) {
        float v = acc[i][j][r];
        if (BF16OUT) ((unsigned short*)Cv)[(size_t)(row0 + r) * N + col] = f2bf(v);
        else         ((float*)Cv)[(size_t)(row0 + r) * N + col] = v;
      }
    }
  }
}

// qkv [B*T, 3*C] bf16 -> rope'd q (pre-scaled by log2e/sqrt(D)) and k, each [B,H,T,D] bf16
__global__ void rope_qk(const unsigned short* __restrict__ qkv,
                        const float* __restrict__ cosb, const float* __restrict__ sinb,
                        unsigned short* __restrict__ qo, unsigned short* __restrict__ ko) {
  int idx = blockIdx.x * blockDim.x + threadIdx.x;
  int d = idx & 31;
  int h = (idx >> 5) & 15;
  int t = (idx >> 9) & 2047;
  int b = idx >> 20;
  const unsigned short* row = qkv + (size_t)(b * TT + t) * (3 * CC);
  float c = cosb[t * DD + d], s = sinb[t * DD + d];
  float q1 = bf2f(row[h * DD + d]),      q2 = bf2f(row[h * DD + d + 32]);
  float k1 = bf2f(row[CC + h * DD + d]), k2 = bf2f(row[CC + h * DD + d + 32]);
  size_t o = (((size_t)(b * HH + h)) * TT + t) * DD + d;
  const float QS = 0.125f * 1.44269504089f;   // 1/sqrt(64) * log2(e): softmax in exp2 domain
  qo[o]      = f2bf(QS * (q1 * c - q2 * s));
  qo[o + 32] = f2bf(QS * (q2 * c + q1 * s));
  ko[o]      = f2bf(k1 * c - k2 * s);
  ko[o + 32] = f2bf(k2 * c + k1 * s);
}

// V slice of qkv -> vt [B,H,D,T] (transposed), LDS tiled, coalesced both sides
__global__ __launch_bounds__(256) void vtrans(const unsigned short* __restrict__ qkv,
                                              unsigned short* __restrict__ vt) {
  __shared__ unsigned short tile[64 * 72];
  const int bh = blockIdx.y, b = bh >> 4, h = bh & 15;
  const int t0 = blockIdx.x * 64;
  const int tid = threadIdx.x;
  const int r = tid >> 2, c0 = (tid & 3) * 16;
  const unsigned short* src = qkv + (size_t)(b * TT + t0 + r) * (3 * CC) + 2 * CC + h * DD + c0;
  *(short8*)&tile[r * 72 + c0]     = *(const short8*)src;
  *(short8*)&tile[r * 72 + c0 + 8] = *(const short8*)(src + 8);
  __syncthreads();
  short8 o0, o1;
  #pragma unroll
  for (int e = 0; e < 8; ++e) {
    ((unsigned short*)&o0)[e] = tile[(c0 + e) * 72 + r];
    ((unsigned short*)&o1)[e] = tile[(c0 + 8 + e) * 72 + r];
  }
  size_t dst = ((size_t)(bh * DD + r)) * TT + t0 + c0;
  *(short8*)&vt[dst]     = o0;
  *(short8*)&vt[dst + 8] = o1;
}

// Flash attention (round 6 structure) + T13 defer-max: skip O-rescale pass when the
// running max didn't grow by >8 (exp2 domain); P bounded by 2^8, safe in bf16/f32.
__global__ __launch_bounds__(256, 3) void attn7(const unsigned short* __restrict__ qb,
                                                const unsigned short* __restrict__ kb,
                                                const unsigned short* __restrict__ vt,
                                                unsigned short* __restrict__ aout) {
  __shared__ unsigned short Kbuf[2][64 * 64];
  __shared__ unsigned short Vbuf[2][64 * 64];
  __shared__ unsigned short Pw[4][16 * 72];
  const int L = blockIdx.x;
  const int xcd = L & 7, m = L >> 3;
  const int bh = xcd * 4 + (m & 3);
  const int qi = 31 - (m >> 2);
  const int qbase = qi * 64;
  const int tid = threadIdx.x, wave = tid >> 6, lane = tid & 63;
  const int g = lane >> 4, lr = lane & 15;
  const unsigned short* Qb  = qb + (size_t)bh * TT * DD;
  const unsigned short* Kb  = kb + (size_t)bh * TT * DD;
  const unsigned short* Vtb = vt + (size_t)bh * DD * TT;
  const int rowbase = qbase + wave * 16;
  const int myq = rowbase + lr;

  short8 qf[2];
  #pragma unroll
  for (int kk = 0; kk < 2; ++kk)
    qf[kk] = *(const short8*)&Qb[(size_t)myq * DD + kk * 32 + g * 8];

  f32x4 acc[4];
  #pragma unroll
  for (int j = 0; j < 4; ++j) acc[j] = (f32x4){0.f, 0.f, 0.f, 0.f};
  float m_i = -1e30f, l_i = 0.f;

  const int srow8 = lane >> 3;
  const int ssw_base = (lane & 7) * 8;

#define STAGE_KV(BUF, TI)                                                                   \
  {                                                                                         \
    const int tt = (TI);                                                                    \
    _Pragma("unroll")                                                                       \
    for (int c = 0; c < 2; ++c) {                                                           \
      const int chunk = wave * 2 + c;                                                       \
      const int row = chunk * 8 + srow8;                                                    \
      const int sw = ssw_base ^ ((row & 7) << 3);                                           \
      __builtin_amdgcn_global_load_lds(                                                     \
        (const __attribute__((address_space(1))) void*)&Kb[(size_t)(tt * 64 + row) * DD + sw], \
        (__attribute__((address_space(3))) void*)&Kbuf[BUF][chunk * 512], 16, 0, 0);        \
      __builtin_amdgcn_global_load_lds(                                                     \
        (const __attribute__((address_space(1))) void*)&Vtb[(size_t)row * TT + tt * 64 + sw], \
        (__attribute__((address_space(3))) void*)&Vbuf[BUF][chunk * 512], 16, 0, 0);        \
    }                                                                                       \
  }

  STAGE_KV(0, 0);
  __syncthreads();

  for (int t = 0; t <= qi; ++t) {
    const int cur = t & 1;
    if (t < qi) STAGE_KV(cur ^ 1, t + 1);

    // ---- S^T = K Q^T : sv[j][r] = S[q=myq][kv=t*64+j*16+g*4+r] ----
    f32x4 sv[4];
    #pragma unroll
    for (int j = 0; j < 4; ++j) sv[j] = (f32x4){0.f, 0.f, 0.f, 0.f};
    #pragma unroll
    for (int kk = 0; kk < 2; ++kk) {
      const int swc = (kk * 32 + g * 8) ^ ((lr & 7) << 3);
      short8 kf[4];
      #pragma unroll
      for (int j = 0; j < 4; ++j)
        kf[j] = *(const short8*)&Kbuf[cur][(j * 16 + lr) * 64 + swc];
      __builtin_amdgcn_s_setprio(1);
      #pragma unroll
      for (int j = 0; j < 4; ++j)
        sv[j] = __builtin_amdgcn_mfma_f32_16x16x32_bf16(kf[j], qf[kk], sv[j], 0, 0, 0);
      __builtin_amdgcn_s_setprio(0);
    }

    if (t == qi) {
      #pragma unroll
      for (int j = 0; j < 4; ++j)
        #pragma unroll
        for (int r = 0; r < 4; ++r)
          if (t * 64 + j * 16 + g * 4 + r > myq) sv[j][r] = -1e30f;
    }

    // ---- lane-local online softmax with defer-max (T13) ----
    float mx = -1e30f;
    #pragma unroll
    for (int j = 0; j < 4; ++j)
      #pragma unroll
      for (int r = 0; r < 4; ++r) mx = fmaxf(mx, sv[j][r]);
    mx = fmaxf(mx, __shfl_xor(mx, 16, 64));
    mx = fmaxf(mx, __shfl_xor(mx, 32, 64));
    if (!__all(mx - m_i <= 8.0f)) {       // wave-uniform: rescale only on real growth
      float mnew = fmaxf(m_i, mx);
      float scl = exp2f(m_i - mnew);
      m_i = mnew;
      l_i *= scl;
      #pragma unroll
      for (int j = 0; j < 4; ++j)
        #pragma unroll
        for (int r = 0; r < 4; ++r) acc[j][r] *= scl;
    }
    float rs = 0.f;
    #pragma unroll
    for (int j = 0; j < 4; ++j)
      #pragma unroll
      for (int r = 0; r < 4; ++r) {
        float p = exp2f(sv[j][r] - m_i);   // bounded by 2^8
        sv[j][r] = p;
        rs += p;
      }
    rs += __shfl_xor(rs, 16, 64);
    rs += __shfl_xor(rs, 32, 64);
    l_i += rs;

    // ---- P -> Pw[q=lr][kv] packed b64 writes ----
    #pragma unroll
    for (int j = 0; j < 4; ++j) {
      uint2 pk;
      pk.x = cvtpk(sv[j][0], sv[j][1]);
      pk.y = cvtpk(sv[j][2], sv[j][3]);
      *(uint2*)&Pw[wave][lr * 72 + j * 16 + g * 4] = pk;
    }
    // ---- O^T += V^T P^T ----
    #pragma unroll
    for (int kk = 0; kk < 2; ++kk) {
      short8 pf = *(const short8*)&Pw[wave][lr * 72 + kk * 32 + g * 8];
      const int swc = (kk * 32 + g * 8) ^ ((lr & 7) << 3);
      short8 vf[4];
      #pragma unroll
      for (int j = 0; j < 4; ++j)
        vf[j] = *(const short8*)&Vbuf[cur][(j * 16 + lr) * 64 + swc];
      __builtin_amdgcn_s_setprio(1);
      #pragma unroll
      for (int j = 0; j < 4; ++j)
        acc[j] = __builtin_amdgcn_mfma_f32_16x16x32_bf16(vf[j], pf, acc[j], 0, 0, 0);
      __builtin_amdgcn_s_setprio(0);
    }
    __syncthreads();
  }
#undef STAGE_KV

  const int b = bh >> 4, h = bh & 15;
  const float inv = 1.0f / l_i;
  size_t rowo = ((size_t)b * TT + myq) * CC + h * DD;
  #pragma unroll
  for (int j = 0; j < 4; ++j) {
    uint2 pk;
    pk.x = cvtpk(acc[j][0] * inv, acc[j][1] * inv);
    pk.y = cvtpk(acc[j][2] * inv, acc[j][3] * inv);
    *(uint2*)&aout[rowo + j * 16 + g * 4] = pk;
  }
}

extern "C" void kernel_launch(void* const* d_in, const int* in_sizes, int n_in,
                              void* d_out, int out_size, void* d_ws, size_t ws_size,
                              hipStream_t stream) {
  const float* x    = (const float*)d_in[0];
  const float* wq   = (const float*)d_in[1];
  const float* wk   = (const float*)d_in[2];
  const float* wv   = (const float*)d_in[3];
  const float* wo   = (const float*)d_in[4];
  const float* cosb = (const float*)d_in[5];
  const float* sinb = (const float*)d_in[6];
  float* out = (float*)d_out;
  char* ws = (char*)d_ws;

  const size_t MB = 1u << 20;
  unsigned short* xb    = (unsigned short*)(ws);              //  8 MB [4096,1024]
  unsigned short* wqkvb = (unsigned short*)(ws + 8 * MB);     //  6 MB [3072,1024]
  unsigned short* wob   = (unsigned short*)(ws + 14 * MB);    //  2 MB [1024,1024]
  unsigned short* sqkv  = (unsigned short*)(ws + 16 * MB);    // 24 MB [4096,3072]
  unsigned short* qb2   = (unsigned short*)(ws + 40 * MB);    //  8 MB [B,H,T,D]
  unsigned short* kb2   = (unsigned short*)(ws + 48 * MB);    //  8 MB [B,H,T,D]
  unsigned short* vtb   = (unsigned short*)(ws + 56 * MB);    //  8 MB [B,H,D,T]
  unsigned short* aoutb = (unsigned short*)(ws + 64 * MB);    //  8 MB [4096,1024]

  cvt_f32_bf16<<<2048, 256, 0, stream>>>(x,  xb, 4194304);
  cvt_f32_bf16<<<1024, 256, 0, stream>>>(wq, wqkvb,           1048576);
  cvt_f32_bf16<<<1024, 256, 0, stream>>>(wk, wqkvb + 1048576, 1048576);
  cvt_f32_bf16<<<1024, 256, 0, stream>>>(wv, wqkvb + 2097152, 1048576);
  cvt_f32_bf16<<<1024, 256, 0, stream>>>(wo, wob,             1048576);

  gemm_bt<true><<<dim3(24, 32), 256, 0, stream>>>(xb, wqkvb, sqkv, 4096, 3072, 1024);
  rope_qk<<<8192, 256, 0, stream>>>(sqkv, cosb, sinb, qb2, kb2);
  vtrans<<<dim3(32, 32), 256, 0, stream>>>(sqkv, vtb);
  attn7<<<1024, 256, 0, stream>>>(qb2, kb2, vtb, aoutb);
  gemm_bt<false><<<dim3(8, 32), 256, 0, stream>>>(aoutb, wob, out, 4096, 1024, 1024);
}